// Round 2
// baseline (390.956 us; speedup 1.0000x reference)
//
#include <hip/hip_runtime.h>
#include <stdint.h>

#define OUTF 4096
#define INF  4096
#define NBAT 2048
#define BM 128
#define BN 128
#define BK 32

typedef __attribute__((ext_vector_type(8))) short bf16x8;   // 8 bf16 = 4 VGPR (guide §3)
typedef __attribute__((ext_vector_type(4))) float f32x4;
typedef __attribute__((ext_vector_type(4))) unsigned int u32x4;

typedef const __attribute__((address_space(1))) uint8_t* gptr_t;
typedef __attribute__((address_space(3))) uint8_t* lptr_t;

// round-to-nearest-even f32 -> bf16 bits (values are tame; no NaN handling needed)
__device__ __forceinline__ uint32_t f2bf(float f) {
  uint32_t u = __builtin_bit_cast(uint32_t, f);
  return (u + 0x7FFFu + ((u >> 16) & 1u)) >> 16;
}

// ---------------- zero W (graph-capture-safe; ws is re-poisoned 0xAA per launch) --
__global__ void zeroW_kernel(uint4* __restrict__ W) {
  W[(size_t)blockIdx.x * 256 + threadIdx.x] = make_uint4(0u, 0u, 0u, 0u);
}

// ---------------- COO scatter-add (sums duplicates, matches .at[].add) ----------
__global__ void scatter_kernel(const float* __restrict__ vals,
                               const int* __restrict__ rows,
                               const int* __restrict__ cols,
                               float* __restrict__ W, int nnz) {
  int i = blockIdx.x * blockDim.x + threadIdx.x;
  if (i < nnz) atomicAdd(&W[(size_t)rows[i] * INF + cols[i]], vals[i]);
}

// ---------------- pack W in place: f32 -> (hi16 << 16) | lo16 -------------------
__global__ void packW_kernel(uint32_t* __restrict__ W) {
  size_t i = ((size_t)blockIdx.x * 256 + threadIdx.x) * 4;
  uint4 p = *(const uint4*)(W + i);
  uint32_t o[4];
  uint32_t w[4] = {p.x, p.y, p.z, p.w};
#pragma unroll
  for (int j = 0; j < 4; ++j) {
    float f = __builtin_bit_cast(float, w[j]);
    uint32_t hi = f2bf(f);
    float fhi = __builtin_bit_cast(float, hi << 16);
    uint32_t lo = f2bf(f - fhi);
    o[j] = (hi << 16) | lo;
  }
  *(uint4*)(W + i) = make_uint4(o[0], o[1], o[2], o[3]);
}

// ---------------- transpose + split X: [K][N] f32 -> Xt_hi/Xt_lo [N][K] bf16 ----
__global__ void packX_kernel(const float* __restrict__ X,
                             uint16_t* __restrict__ Xh,
                             uint16_t* __restrict__ Xl) {
  __shared__ float t[32][33];
  int n0 = blockIdx.x * 32, k0 = blockIdx.y * 32;
  int tx = threadIdx.x, ty = threadIdx.y;  // 32 x 8
#pragma unroll
  for (int j = 0; j < 4; ++j)
    t[ty + j * 8][tx] = X[(size_t)(k0 + ty + j * 8) * NBAT + n0 + tx];
  __syncthreads();
#pragma unroll
  for (int j = 0; j < 4; ++j) {
    int n = n0 + ty + j * 8, k = k0 + tx;
    float f = t[tx][ty + j * 8];
    uint32_t hi = f2bf(f);
    float fhi = __builtin_bit_cast(float, hi << 16);
    uint32_t lo = f2bf(f - fhi);
    Xh[(size_t)n * INF + k] = (uint16_t)hi;
    Xl[(size_t)n * INF + k] = (uint16_t)lo;
  }
}

// ---------------- split-bf16 GEMM: out = Whi*Xhi + Whi*Xlo + Wlo*Xhi + bias -----
// A tile (LDS): [128 rows][32 packed u32] = 128B/row.  Logical 16B chunk c of row
// r lives at physical chunk c ^ (r&7) (both the global_load_lds SOURCE and the
// ds_read use the same involution -> linear LDS dest, conflict-free reads: each
// wave access lands 8 words on every bank, the 1024B/instr minimum).
// B tile (LDS): [128 cols][plane(2)][32 k] bf16 = 128B/row, same swizzle.
__global__ __launch_bounds__(256, 2) void gemm_kernel(
    const uint32_t* __restrict__ Wp,   // [OUTF][INF] packed hi|lo
    const uint16_t* __restrict__ Xh,   // [NBAT][INF] bf16 bits
    const uint16_t* __restrict__ Xl,
    const float* __restrict__ bias,
    float* __restrict__ out) {         // [OUTF][NBAT]
  __shared__ __align__(16) uint8_t lds[32768];
  uint8_t* la = lds;            // 16KB A
  uint8_t* lb = lds + 16384;    // 16KB B

  const unsigned tid = threadIdx.x;
  const unsigned lane = tid & 63, wid = tid >> 6;
  const unsigned wr = wid >> 1, wc = wid & 1;

  // XCD-aware bijective remap (512 % 8 == 0), m-fastest so each XCD owns 2
  // B column-panels (4MB Xh+Xl, L2-resident) and streams A through L3.
  unsigned newid = (blockIdx.x & 7) * 64 + (blockIdx.x >> 3);
  const unsigned bm = newid & 31, bn = newid >> 5;

  // ---- staging source pointers (per-lane, pre-swizzled global addresses) ----
  const uint8_t* aSrc[4];
  const uint8_t* bSrc[4];
#pragma unroll
  for (int i = 0; i < 4; ++i) {
    unsigned d = i * 4096 + tid * 16;     // linear LDS byte this lane fills
    unsigned row = d >> 7;                // tile row (A) / tile col (B)
    unsigned ch = (d >> 4) & 7;           // 16B chunk within 128B row
    unsigned sc = ch ^ (row & 7);         // swizzled source chunk
    aSrc[i] = (const uint8_t*)Wp + (size_t)(bm * BM + row) * (INF * 4) + sc * 16;
    const uint16_t* base = (sc & 4) ? Xl : Xh;        // plane from swizzled chunk
    bSrc[i] = (const uint8_t*)(base + (size_t)(bn * BN + row) * INF + (sc & 3) * 8);
  }

  // ---- kt-invariant fragment LDS byte offsets (hoisted out of k-loop) ----
  const unsigned kg = lane >> 4, lr = lane & 15;
  unsigned aOff[4][2], bOffH[4], bOffL[4];
#pragma unroll
  for (int mi = 0; mi < 4; ++mi) {
    unsigned row = wr * 64 + mi * 16 + lr;
    aOff[mi][0] = row * 128 + (((kg * 2 + 0) ^ (row & 7)) * 16);
    aOff[mi][1] = row * 128 + (((kg * 2 + 1) ^ (row & 7)) * 16);
  }
#pragma unroll
  for (int ni = 0; ni < 4; ++ni) {
    unsigned col = wc * 64 + ni * 16 + lr;
    bOffH[ni] = col * 128 + (((0 + kg) ^ (col & 7)) * 16);  // plane 0 (hi)
    bOffL[ni] = col * 128 + (((4 + kg) ^ (col & 7)) * 16);  // plane 1 (lo)
  }

  f32x4 acc[4][4] = {};

  for (unsigned kt = 0; kt < INF / BK; ++kt) {
    // stage A (16KB) + B (16KB); dest is wave-uniform base + lane*16 (implicit)
#pragma unroll
    for (int i = 0; i < 4; ++i) {
      __builtin_amdgcn_global_load_lds((gptr_t)(aSrc[i] + (size_t)kt * 128),
                                       (lptr_t)(la + i * 4096 + wid * 1024), 16, 0, 0);
      __builtin_amdgcn_global_load_lds((gptr_t)(bSrc[i] + (size_t)kt * 64),
                                       (lptr_t)(lb + i * 4096 + wid * 1024), 16, 0, 0);
    }
    __syncthreads();  // compiler drains vmcnt before s_barrier

    bf16x8 ah[4], al[4], bh[4], bl[4];
#pragma unroll
    for (int mi = 0; mi < 4; ++mi) {
      uint4 p0 = *(const uint4*)(la + aOff[mi][0]);
      uint4 p1 = *(const uint4*)(la + aOff[mi][1]);
      u32x4 h, l;
      h[0] = (p0.x >> 16) | (p0.y & 0xFFFF0000u);  l[0] = (p0.x & 0xFFFFu) | (p0.y << 16);
      h[1] = (p0.z >> 16) | (p0.w & 0xFFFF0000u);  l[1] = (p0.z & 0xFFFFu) | (p0.w << 16);
      h[2] = (p1.x >> 16) | (p1.y & 0xFFFF0000u);  l[2] = (p1.x & 0xFFFFu) | (p1.y << 16);
      h[3] = (p1.z >> 16) | (p1.w & 0xFFFF0000u);  l[3] = (p1.z & 0xFFFFu) | (p1.w << 16);
      ah[mi] = __builtin_bit_cast(bf16x8, h);
      al[mi] = __builtin_bit_cast(bf16x8, l);
    }
#pragma unroll
    for (int ni = 0; ni < 4; ++ni) {
      bh[ni] = *(const bf16x8*)(lb + bOffH[ni]);
      bl[ni] = *(const bf16x8*)(lb + bOffL[ni]);
    }
#pragma unroll
    for (int mi = 0; mi < 4; ++mi)
#pragma unroll
      for (int ni = 0; ni < 4; ++ni) {
        acc[mi][ni] = __builtin_amdgcn_mfma_f32_16x16x32_bf16(ah[mi], bh[ni], acc[mi][ni], 0, 0, 0);
        acc[mi][ni] = __builtin_amdgcn_mfma_f32_16x16x32_bf16(ah[mi], bl[ni], acc[mi][ni], 0, 0, 0);
        acc[mi][ni] = __builtin_amdgcn_mfma_f32_16x16x32_bf16(al[mi], bh[ni], acc[mi][ni], 0, 0, 0);
      }
    __syncthreads();  // all reads done before next stage overwrites
  }

  // ---- epilogue: C/D layout col=lane&15, row=4*(lane>>4)+reg (verified m89) ----
  const unsigned lq = lane >> 4;
#pragma unroll
  for (int mi = 0; mi < 4; ++mi) {
    unsigned row0 = bm * BM + wr * 64 + mi * 16 + lq * 4;
#pragma unroll
    for (int ni = 0; ni < 4; ++ni) {
      unsigned col = bn * BN + wc * 64 + ni * 16 + lr;
#pragma unroll
      for (int r = 0; r < 4; ++r)
        out[(size_t)(row0 + r) * NBAT + col] = acc[mi][ni][r] + bias[row0 + r];
    }
  }
}

extern "C" void kernel_launch(void* const* d_in, const int* in_sizes, int n_in,
                              void* d_out, int out_size, void* d_ws, size_t ws_size,
                              hipStream_t stream) {
  const float* inp    = (const float*)d_in[0];  // [INF][NBAT]
  const float* values = (const float*)d_in[1];  // [nnz]
  const float* bias   = (const float*)d_in[2];  // [OUTF]
  const int*   rows   = (const int*)d_in[3];
  const int*   cols   = (const int*)d_in[4];
  const int nnz = in_sizes[1];
  float* out = (float*)d_out;

  uint8_t* ws = (uint8_t*)d_ws;
  float*    W  = (float*)ws;                               // 64 MB (fp32 -> packed in place)
  uint16_t* Xh = (uint16_t*)(ws + (64u << 20));            // 16 MB
  uint16_t* Xl = (uint16_t*)(ws + (80u << 20));            // 16 MB

  zeroW_kernel<<<(OUTF * (size_t)INF * 4) / (256 * 16), 256, 0, stream>>>((uint4*)W);
  scatter_kernel<<<(nnz + 255) / 256, 256, 0, stream>>>(values, rows, cols, W, nnz);
  packW_kernel<<<(OUTF * (size_t)INF / 4) / 256, 256, 0, stream>>>((uint32_t*)W);
  packX_kernel<<<dim3(NBAT / 32, INF / 32), dim3(32, 8), 0, stream>>>(inp, Xh, Xl);
  gemm_kernel<<<(OUTF / BM) * (NBAT / BN), 256, 0, stream>>>(
      (const uint32_t*)W, Xh, Xl, bias, out);
}